// Round 10
// baseline (227.499 us; speedup 1.0000x reference)
//
#include <hip/hip_runtime.h>

typedef unsigned short u16;
typedef unsigned int   u32;

typedef short shortx8   __attribute__((ext_vector_type(8)));
typedef float floatx4   __attribute__((ext_vector_type(4)));
typedef float floatx16  __attribute__((ext_vector_type(16)));
typedef u32   uintx2    __attribute__((ext_vector_type(2)));
typedef u32   uintx4    __attribute__((ext_vector_type(4)));

typedef u32     u32a     __attribute__((may_alias));
typedef uintx2  uintx2a  __attribute__((may_alias));
typedef uintx4  uintx4a  __attribute__((may_alias));
typedef shortx8 shortx8a __attribute__((may_alias));

// accurate round-to-nearest-even (weights)
__device__ __forceinline__ u16 f2bf(float f){
  union { float f; u32 i; } v; v.f = f;
  return (u16)((v.i + 0x7fffu + ((v.i >> 16) & 1u)) >> 16);
}
// fast round-half-up (scalar hot path; max 0.5 ulp)
__device__ __forceinline__ u16 f2bf_fast(float f){
  union { float f; u32 i; } v; v.f = f;
  return (u16)((v.i + 0x8000u) >> 16);
}
// pack two bf16 via v_perm (3 VALU ops) — fallback
__device__ __forceinline__ u32 pack2(float lo, float hi){
  union { float f; u32 i; } a, b; a.f = lo; b.f = hi;
  return __builtin_amdgcn_perm(b.i + 0x8000u, a.i + 0x8000u, 0x07060302u);
}
// packed f32->bf16 convert: 1 VALU op on gfx950 (v_cvt_pk_bf16_f32), RNE
__device__ __forceinline__ u32 cvtpk2(float lo, float hi){
#if __has_builtin(__builtin_amdgcn_cvt_pk_bf16_f32)
  auto pv = __builtin_amdgcn_cvt_pk_bf16_f32(lo, hi);
  if constexpr (sizeof(pv) == 4){
    u32 out; __builtin_memcpy(&out, &pv, 4); return out;
  } else {
    return pack2(lo, hi);
  }
#else
  return pack2(lo, hi);
#endif
}
__device__ __forceinline__ float lrelu(float v){ return fmaxf(v, 0.01f*v); }

// ---------------------------------------------------------------------------
// Kernel 1: fused conv1 -> conv2 -> conv3, all on MFMA — ROUND-16 structure,
// EXACT R4/R9 binary (session best: 193.0 µs total). Also zeroes the xl/l1
// split-K accumulators (one float per thread, exact coverage).
// grid (16 t-pairs, 16 b-groups, 15 nodes), block 256 (2 wave-pairs).
// ---------------------------------------------------------------------------
__global__ void __launch_bounds__(256, 4) fused_conv(
    const float* __restrict__ X,
    const float* __restrict__ w1, const float* __restrict__ b1,
    const float* __restrict__ w2, const float* __restrict__ b2,
    const float* __restrict__ w3, const float* __restrict__ b3,
    u16* __restrict__ h3p, u16* __restrict__ Xb,
    const float* __restrict__ lw, u16* __restrict__ lwb,
    const float* __restrict__ gw, u16* __restrict__ gwp,
    float* __restrict__ xlz, float* __restrict__ l1z){
  const int tid  = threadIdx.x;
  const int node = blockIdx.z;
  const int p0   = blockIdx.x * 120;
  const int b0   = blockIdx.y * 8;

  // per-pair region: [0..1631] = H1 (68 rows x 24), [1632..4351] = H2 (68 x 40)
  // pads: H1 cols 16..23 = BtW rows 0..67; H2 cols 32..39 = BtW rows 68..135
  __shared__ __attribute__((aligned(16))) u16 sPair[2][4352];
  __shared__ __attribute__((aligned(16))) u16 sW2f[2560];   // [tap][kh][oc32][j8]
  __shared__ __attribute__((aligned(16))) u16 sW3f[160];    // [tap][ic32]
  __shared__ __attribute__((aligned(16))) u16 sXb[8*136];   // bf16 X window (120+16)
  __shared__ float sW1[80], sB1[16], sB2[32];

  // ---- distributed prep: 256 elements per block, exact coverage; also
  //      zero xl/l1 (split-K atomic accumulators) ----
  {
    const int bid = blockIdx.x + 16*(blockIdx.y + 16*blockIdx.z);  // 0..3839
    int gid = bid*256 + tid;                   // 0..983039
    if (gid < 491520){
      lwb[gid] = f2bf(lw[gid]);                // lin1_w: 256*1920 elements
      xlz[gid] = 0.f;
    } else {
      int g2 = gid - 491520;                   // 0..491519 (gwp elements)
      int row = g2 / 1920;                     // 0..255
      int col = g2 - row*1920;
      gwp[g2] = (col < 1908) ? f2bf(gw[row*1908 + col]) : (u16)0;
      l1z[g2] = 0.f;
    }
  }

  // ---- staging ----
  {
    const int bls = tid >> 5, i0 = tid & 31;   // 8 batches x 32 threads
    const float* xrow = X  + (size_t)((b0 + bls)*15 + node)*1920;
    u16*        xbrow = Xb + (size_t)((b0 + bls)*15 + node)*1920;
    #pragma unroll
    for (int u = 0; u < 5; ++u){
      int i = i0 + 32*u;
      if (i < 136){
        int g = p0 + i;
        float xv = (g < 1920) ? xrow[g] : 0.f;
        u16 xb = f2bf_fast(xv);
        sXb[bls*136 + i] = xb;
        if (i < 120) xbrow[g] = xb;   // i<120 => g<1920 always
      }
    }
    // w2 into 32x32 A-frag order: idx = ((tap*2 + kh)*32 + oc)*8 + j
    #pragma unroll
    for (int u = 0; u < 10; ++u){
      int d = tid + 256*u;
      int j = d & 7, oc = (d >> 3) & 31, kh = (d >> 8) & 1, tap = d >> 9; // 0..4
      sW2f[d] = f2bf(w2[node*2560 + (oc*16 + kh*8 + j)*5 + tap]);
    }
    if (tid < 160){
      int icc = tid / 5, tp = tid - 5*icc;
      sW3f[tp*32 + icc] = f2bf(w3[node*160 + tid]);
    }
    if (tid < 80) sW1[tid] = w1[node*80 + tid];
    if (tid < 16) sB1[tid] = b1[node*16 + tid];
    if (tid < 32) sB2[tid] = b2[node*32 + tid];
    // zero sH2 tail rows 64..67, cols 0..31 ONLY (cols 32..39 are BtW pad —
    // must not race with the per-bb BtW build). 2 pairs x 128 u16 = 256.
    {
      const int pr = tid >> 7, idx = tid & 127;
      sPair[pr][1632 + (64 + (idx >> 5))*40 + (idx & 31)] = 0;
    }
  }
  __syncthreads();

  const int w = tid >> 6, lane = tid & 63;
  const int pw = w >> 1, ph = w & 1;          // pair index (0..1) / pair half
  const int m = lane & 15, quad = lane >> 4;  // 16x16 roles
  const int t32 = lane & 31, kh = lane >> 5;  // 32x32 roles (kh = k-half)

  // conv2 A-frags (32x32x16): A[m=oc=lane&31][k=kh*8+j]
  shortx8 a2t[5];
  #pragma unroll
  for (int tap = 0; tap < 5; ++tap)
    a2t[tap] = *(const shortx8a*)&sW2f[((tap*2 + kh)*32 + t32)*8];

  // conv2 bias per accumulator reg: row(oc) = (r&3) + 8*(r>>2) + 4*kh
  float biasr[16];
  #pragma unroll
  for (int r = 0; r < 16; ++r)
    biasr[r] = sB2[(r&3) + 8*(r>>2) + 4*kh];

  // conv3 A-frags (16x16x32): only row m=0 nonzero
  shortx8 a3[5];
  {
    const shortx8 zv = {0,0,0,0,0,0,0,0};
    #pragma unroll
    for (int tp = 0; tp < 5; ++tp){
      shortx8 t = *(const shortx8a*)&sW3f[tp*32 + quad*8];
      a3[tp] = (m == 0) ? t : zv;
    }
  }
  const float b3v = b3[node];

  // conv1 A-frags (16x16x32): A[oc=lane&15][k=quad*8+j], taps k<5 only ->
  // quad 0 carries data, quads 1..3 zero. hi+lo bf16 split of f32 weights.
  shortx8 a1h = {0,0,0,0,0,0,0,0}, a1l = {0,0,0,0,0,0,0,0};
  if (quad == 0){
    const float* wrow = sW1 + m*5;
    #pragma unroll
    for (int j = 0; j < 5; ++j){
      float wv = wrow[j];
      u16 h = f2bf(wv);
      union { u32 i; float f; } hf; hf.i = ((u32)h) << 16;
      u16 l = f2bf(wv - hf.f);
      a1h[j] = (short)h; a1l[j] = (short)l;
    }
  }
  // conv1 bias per acc reg: D row(oc) = quad*4 + r
  float biasA[4];
  #pragma unroll
  for (int r = 0; r < 4; ++r) biasA[r] = sB1[quad*4 + r];

  u16* h1w = sPair[pw];           // pair region base (H1 at 0, H2 at 1632)
  u16* h2w = sPair[pw] + 1632;

  for (int bb = 0; bb < 4; ++bb){
    const int bl = pw + bb*2;   // 0..7
    const int rg = (b0 + bl)*15 + node;

    // ---- build BtW im2col rows into the H1/H2 pads (once per bb) ----
    // BtW[t][k] = sXb[bl*136 + t + k], t 0..135, k 0..7 (zero beyond window).
    {
      const int s = tid & 127;                 // lane-in-pair
      if (s < 68){
        const u32* xb32 = (const u32*)sXb + bl*68;
        u32 r0 = xb32[s];
        u32 r1 = (s+1 < 68) ? xb32[s+1] : 0u;
        u32 r2 = (s+2 < 68) ? xb32[s+2] : 0u;
        u32 r3 = (s+3 < 68) ? xb32[s+3] : 0u;
        u32 r4 = (s+4 < 68) ? xb32[s+4] : 0u;
        const int te = 2*s, to = 2*s + 1;      // both rows same region (s<34)
        const int offE = (s < 34) ? te*24 + 16 : 1632 + (te - 68)*40 + 32;
        const int offO = (s < 34) ? to*24 + 16 : 1632 + (to - 68)*40 + 32;
        uintx4 ve = {r0, r1, r2, r3};
        uintx4 vo = {__builtin_amdgcn_alignbit(r1, r0, 16),
                     __builtin_amdgcn_alignbit(r2, r1, 16),
                     __builtin_amdgcn_alignbit(r3, r2, 16),
                     __builtin_amdgcn_alignbit(r4, r3, 16)};
        *(uintx4a*)(h1w + offE) = ve;
        *(uintx4a*)(h1w + offO) = vo;
      }
    }
    __syncthreads();   // BtW build -> conv1 frag reads

    #pragma unroll
    for (int tt = 0; tt < 2; ++tt){
      const int p = p0 + tt*60;

      // ---- conv1 (MFMA 16x16x32): D[oc][t] tiles of 16 t; wave ph=0 does
      // tiles {0,2,4}, ph=1 does {1,3}; 2 MFMAs (w1 lo+hi) per tile ----
      #pragma unroll
      for (int ti = 0; ti < 3; ++ti){
        const int T = ph + 2*ti;
        if (T < 5){
          const int tr = T*16 + m;             // output t (valid < 68)
          int row = tt*60 + tr;                // BtW row
          row = row > 135 ? 135 : row;         // clamp (garbage rows guarded)
          shortx8 bfr = {0,0,0,0,0,0,0,0};
          if (quad == 0){
            const int off = (row < 68) ? row*24 + 16 : 1632 + (row - 68)*40 + 32;
            bfr = *(const shortx8a*)(h1w + off);
          }
          floatx4 acc = {biasA[0], biasA[1], biasA[2], biasA[3]};
          acc = __builtin_amdgcn_mfma_f32_16x16x32_bf16(a1l, bfr, acc, 0, 0, 0);
          acc = __builtin_amdgcn_mfma_f32_16x16x32_bf16(a1h, bfr, acc, 0, 0, 0);
          if (tr < 68){
            uintx2 pk = { cvtpk2(lrelu(acc[0]), lrelu(acc[1])),
                          cvtpk2(lrelu(acc[2]), lrelu(acc[3])) };
            *(uintx2a*)(h1w + tr*24 + quad*4) = pk;   // [t][oc] b64, 8B aligned
          }
        }
      }
      __syncthreads();   // conv1 writes -> conv2 reads

      // ---- conv2 (32x32x16): tile nt=ph, 5 tap MFMAs, bias in acc ----
      {
        const int t0 = ph*32;
        floatx16 acc;
        #pragma unroll
        for (int r = 0; r < 16; ++r) acc[r] = biasr[r];
        #pragma unroll
        for (int tap = 0; tap < 5; ++tap){
          shortx8 bfr = *(const shortx8a*)(h1w + (t0 + t32 + tap)*24 + kh*8);
          acc = __builtin_amdgcn_mfma_f32_32x32x16_bf16(a2t[tap], bfr, acc, 0, 0, 0);
        }
        // D: col(t)=lane&31, row(oc)=(r&3)+8*(r>>2)+4*kh; r-pairs = oc pairs
        u16* dst = h2w + (t0 + t32)*40;
        #pragma unroll
        for (int r = 0; r < 16; r += 2){
          float v0 = lrelu(acc[r]);
          float v1 = lrelu(acc[r+1]);
          const int oc0 = (r&3) + 8*(r>>2) + 4*kh;
          *(u32a*)(dst + oc0) = cvtpk2(v0, v1);
        }
      }
      __syncthreads();   // conv2 writes -> conv3 reads

      // ---- conv3 (16x16x32): tiles {2ph, 2ph+1}, 5 tap MFMAs; D row 0 ----
      #pragma unroll
      for (int i = 0; i < 2; ++i){
        const int nt = 2*ph + i;
        floatx4 acc3 = {0.f,0.f,0.f,0.f};
        if (lane < 16) acc3[0] = b3v;
        #pragma unroll
        for (int tp = 0; tp < 5; ++tp){
          shortx8 bfr = *(const shortx8a*)(h2w + (nt*16 + m + tp)*40 + quad*8);
          acc3 = __builtin_amdgcn_mfma_f32_16x16x32_bf16(a3[tp], bfr, acc3, 0, 0, 0);
        }
        const int tl = nt*16 + lane;
        if (lane < 16 && tl < 60){
          const int t3 = p + tl;           // max 15*120+60+59 = 1919 < 1920
          float v = lrelu(acc3[0]);
          h3p[(size_t)rg*1920 + t3] = (t3 < 1908) ? f2bf_fast(v) : (u16)0;
        }
      }
    }
  }
}

// ---------------------------------------------------------------------------
// Kernel 2: NT GEMM, split-K x2 + ping-pong LDS (R4 inner loop, unchanged).
// ROUND-23: one launch PER JOB so the two jobs can run on forked streams
// (job0 = l1, consumed only by finalize_k, overlaps job1+gcn_agg).
// grid (30,4,2): z = khalf; atomicAdd into pre-zeroed output (2-way per
// address). gZ non-null (job1 launch) -> block (0,0,0) zeroes gS/gS2.
// ---------------------------------------------------------------------------
__global__ void __launch_bounds__(256) gemm_nt(
    const u16* __restrict__ A, const u16* __restrict__ Bm,
    float* __restrict__ O, float* __restrict__ gZ){
  const int khf = blockIdx.z;
  __shared__ __attribute__((aligned(16))) u16 sA[2][64*88];
  __shared__ __attribute__((aligned(16))) u16 sB[2][64*88];
  const int tid = threadIdx.x;
  if (gZ != nullptr && blockIdx.x == 0 && blockIdx.y == 0 && blockIdx.z == 0){
    #pragma unroll
    for (int u = 0; u < 30; ++u) gZ[tid + 256*u] = 0.f;
  }
  const int m0 = blockIdx.x*64, n0 = blockIdx.y*64;
  const int row = tid >> 2, kc = tid & 3;
  const int w = tid >> 6, lane = tid & 63;
  const int m = lane & 15, quad = lane >> 4;
  const int mo = (w & 1)*32, no = (w >> 1)*32;
  floatx4 acc[2][2];
  #pragma unroll
  for (int i = 0; i < 2; ++i)
    #pragma unroll
    for (int j = 0; j < 2; ++j)
      #pragma unroll
      for (int r = 0; r < 4; ++r) acc[i][j][r] = 0.f;

  const u16* ap = A  + (size_t)(m0 + row)*1920 + khf*960 + kc*8;
  const u16* bp = Bm + (size_t)(n0 + row)*1920 + khf*960 + kc*8;
  // preload kt=0
  uintx4 va0 = *(const uintx4a*)ap;
  uintx4 va1 = *(const uintx4a*)(ap + 32);
  uintx4 vb0 = *(const uintx4a*)bp;
  uintx4 vb1 = *(const uintx4a*)(bp + 32);
  ap += 64; bp += 64;

  for (int kt = 0; kt < 15; ++kt){
    const int c = kt & 1;
    *(uintx4a*)&sA[c][row*88 + kc*8]      = va0;
    *(uintx4a*)&sA[c][row*88 + 32 + kc*8] = va1;
    *(uintx4a*)&sB[c][row*88 + kc*8]      = vb0;
    *(uintx4a*)&sB[c][row*88 + 32 + kc*8] = vb1;
    __syncthreads();
    if (kt < 14){
      va0 = *(const uintx4a*)ap;
      va1 = *(const uintx4a*)(ap + 32);
      vb0 = *(const uintx4a*)bp;
      vb1 = *(const uintx4a*)(bp + 32);
      ap += 64; bp += 64;
    }
    #pragma unroll
    for (int ks = 0; ks < 64; ks += 32){
      const shortx8 af0 = *(const shortx8a*)&sA[c][(mo      + m)*88 + ks + quad*8];
      const shortx8 af1 = *(const shortx8a*)&sA[c][(mo + 16 + m)*88 + ks + quad*8];
      const shortx8 bf0 = *(const shortx8a*)&sB[c][(no      + m)*88 + ks + quad*8];
      const shortx8 bf1 = *(const shortx8a*)&sB[c][(no + 16 + m)*88 + ks + quad*8];
      acc[0][0] = __builtin_amdgcn_mfma_f32_16x16x32_bf16(af0, bf0, acc[0][0], 0, 0, 0);
      acc[0][1] = __builtin_amdgcn_mfma_f32_16x16x32_bf16(af0, bf1, acc[0][1], 0, 0, 0);
      acc[1][0] = __builtin_amdgcn_mfma_f32_16x16x32_bf16(af1, bf0, acc[1][0], 0, 0, 0);
      acc[1][1] = __builtin_amdgcn_mfma_f32_16x16x32_bf16(af1, bf1, acc[1][1], 0, 0, 0);
    }
    // ping-pong: buf c rewritten only at kt+2; reads complete before the
    // kt+1 barrier in same-wave program order.
  }
  #pragma unroll
  for (int mi = 0; mi < 2; ++mi)
    #pragma unroll
    for (int ni = 0; ni < 2; ++ni)
      #pragma unroll
      for (int r = 0; r < 4; ++r){
        int rr = m0 + mo + mi*16 + quad*4 + r;
        int cc = n0 + no + ni*16 + m;
        atomicAdd(&O[(size_t)rr*256 + cc], acc[mi][ni][r]);
      }
}

// ---------------------------------------------------------------------------
// Kernel 3: GCN aggregation + bias, plus per-(n,c) GraphNorm stat
// accumulation (atomicAdd of T and T^2 into gS/gS2, zeroed by gemm job1).
// ---------------------------------------------------------------------------
__global__ void __launch_bounds__(256) gcn_agg(
    const float* __restrict__ xl, const int* __restrict__ ei,
    const float* __restrict__ ew, const float* __restrict__ gcn_b,
    float* __restrict__ Tpre, float* __restrict__ gS, float* __restrict__ gS2){
  const int b = blockIdx.x, tid = threadIdx.x;
  __shared__ float sxl[15*256];
  __shared__ float s_deg[15], s_dinv[15], s_norm[71];
  __shared__ int   s_cnt[15], s_start[16], s_fill[15], s_srcl[71];
  if (tid < 15){ s_deg[tid] = 0.f; s_cnt[tid] = 0; s_fill[tid] = 0; }
  #pragma unroll
  for (int n = 0; n < 15; ++n)
    sxl[n*256 + tid] = xl[(size_t)(b*15 + n)*256 + tid];
  __syncthreads();
  int se = 0, de = 0; float we = 0.f;
  if (tid < 71){
    if (tid < 56){ se = ei[tid]; de = ei[56 + tid]; we = ew[tid]; }
    else         { se = tid - 56; de = tid - 56; we = 1.0f; }
    atomicAdd(&s_deg[de], we);
    atomicAdd(&s_cnt[de], 1);
  }
  __syncthreads();
  if (tid < 15) s_dinv[tid] = s_deg[tid] > 0.f ? rsqrtf(s_deg[tid]) : 0.f;
  if (tid == 0){
    int a = 0;
    for (int n = 0; n < 15; ++n){ s_start[n] = a; a += s_cnt[n]; }
    s_start[15] = a;
  }
  __syncthreads();
  if (tid < 71){
    float nrm = s_dinv[se]*we*s_dinv[de];
    int pos = s_start[de] + atomicAdd(&s_fill[de], 1);
    s_srcl[pos] = se; s_norm[pos] = nrm;
  }
  __syncthreads();
  const float gb = gcn_b[tid];
  for (int n = 0; n < 15; ++n){
    float acc = gb;
    const int e0 = s_start[n], e1 = s_start[n+1];
    for (int idx = e0; idx < e1; ++idx)
      acc += s_norm[idx]*sxl[s_srcl[idx]*256 + tid];
    Tpre[(size_t)(b*15 + n)*256 + tid] = acc;
    atomicAdd(&gS [n*256 + tid], acc);
    atomicAdd(&gS2[n*256 + tid], acc*acc);
  }
}

// ---------------------------------------------------------------------------
// Kernel 4: GraphNorm (stats from gS/gS2) + lin1-add + ELU + pool + head
// ---------------------------------------------------------------------------
__global__ void __launch_bounds__(256) finalize_k(
    const float* __restrict__ Tpre, const float* __restrict__ l1,
    const float* __restrict__ gS, const float* __restrict__ gS2,
    const float* __restrict__ gn_ms, const float* __restrict__ gn_w,
    const float* __restrict__ gn_b, const float* __restrict__ lin1_b,
    const float* __restrict__ out_w, const float* __restrict__ out_b,
    float* __restrict__ dout){
  const int b = blockIdx.x, tid = threadIdx.x;
  __shared__ float spool[256], spart[256];
  const float gnb = gn_b[tid], lb = lin1_b[tid];
  const float gms = gn_ms[tid], gwc = gn_w[tid];
  float acc = 0.f;
  #pragma unroll
  for (int n = 0; n < 15; ++n){
    const float s  = gS [n*256 + tid];
    const float s2 = gS2[n*256 + tid];
    const float mean = s*(1.f/128.f);
    const float mo   = mean*gms;
    float var = s2*(1.f/128.f) - 2.f*mo*mean + mo*mo;
    var = fmaxf(var, 0.f);
    const float scal = gwc*rsqrtf(var + 1e-5f);
    float t = (Tpre[(size_t)(b*15 + n)*256 + tid] - mo)*scal
              + gnb + l1[(size_t)(b*15 + n)*256 + tid] + lb;
    t = t > 0.f ? t : (__expf(t) - 1.f);   // ELU(alpha=1)
    acc += t;
  }
  const float pool = acc*(1.f/15.f);
  dout[b*256 + tid] = pool;
  spool[tid] = pool;
  __syncthreads();
  const int j = tid >> 4, q = tid & 15;
  float s = 0.f;
  for (int i = 0; i < 16; ++i){
    int cc = q + i*16;
    s += spool[cc]*out_w[j*256 + cc];
  }
  spart[tid] = s;
  __syncthreads();
  if (tid < 16){
    float tot = out_b[tid];
    #pragma unroll
    for (int i = 0; i < 16; ++i) tot += spart[tid*16 + i];
    dout[32768 + b*16 + tid] = tot;
  }
}

// ---------------------------------------------------------------------------
extern "C" void kernel_launch(void* const* d_in, const int* in_sizes, int n_in,
                              void* d_out, int out_size, void* d_ws, size_t ws_size,
                              hipStream_t stream){
  (void)in_sizes; (void)n_in; (void)out_size; (void)ws_size;
  const float* X    = (const float*)d_in[0];
  const int*   ei   = (const int*)d_in[1];
  const float* ew   = (const float*)d_in[2];
  const float* w1   = (const float*)d_in[3];
  const float* b1   = (const float*)d_in[4];
  const float* w2   = (const float*)d_in[5];
  const float* b2   = (const float*)d_in[6];
  const float* w3   = (const float*)d_in[7];
  const float* b3   = (const float*)d_in[8];
  const float* gw   = (const float*)d_in[9];
  const float* gb   = (const float*)d_in[10];
  const float* lw   = (const float*)d_in[11];
  const float* lb   = (const float*)d_in[12];
  const float* gnw  = (const float*)d_in[13];
  const float* gnb  = (const float*)d_in[14];
  const float* gnms = (const float*)d_in[15];
  const float* ow   = (const float*)d_in[16];
  const float* ob   = (const float*)d_in[17];

  char* ws = (char*)d_ws;
  u16*   h3p  = (u16*)(ws + 0);              //  7,372,800 B
  u16*   gwp  = (u16*)(ws + 7372800);        //    983,040 B (491,520 u16)
  u16*   Xb   = (u16*)(ws + 8355840);        //  7,372,800 B
  u16*   lwb  = (u16*)(ws + 15728640);       //    983,040 B (491,520 u16)
  float* xl   = (float*)(ws + 16711680);     //  1,966,080 B
  float* l1   = (float*)(ws + 18677760);     //  1,966,080 B
  float* gS   = (float*)(ws + 20643840);     //     15,360 B
  float* gS2  = (float*)(ws + 20659200);     //     15,360 B (end 20,674,560)
  float* Tpre = (float*)(ws + 0);            // reuse h3p (dead after gemm)

  // One-time side-stream + events for the fork-join (host-side resource
  // creation — legal during capture; the recorded event edges become graph
  // dependencies). Fallback to the sequential R9 chain if creation fails.
  static hipStream_t s2 = nullptr;
  static hipEvent_t  evFc = nullptr, evJ0 = nullptr;
  static int mstream_ok = -1;
  if (mstream_ok < 0){
    mstream_ok =
      (hipStreamCreateWithFlags(&s2, hipStreamNonBlocking) == hipSuccess &&
       hipEventCreateWithFlags(&evFc, hipEventDisableTiming) == hipSuccess &&
       hipEventCreateWithFlags(&evJ0, hipEventDisableTiming) == hipSuccess) ? 1 : 0;
  }

  fused_conv<<<dim3(16, 16, 15), dim3(256), 0, stream>>>(X, w1, b1, w2, b2, w3, b3,
                                                         h3p, Xb, lw, lwb, gw, gwp,
                                                         xl, l1);
  if (mstream_ok == 1){
    // fork: job0 (l1, only needed by finalize) on s2; job1 -> gcn_agg on main
    hipEventRecord(evFc, stream);
    hipStreamWaitEvent(s2, evFc, 0);
    gemm_nt<<<dim3(30, 4, 2), dim3(256), 0, s2>>>(Xb, lwb, l1, (float*)nullptr);
    gemm_nt<<<dim3(30, 4, 2), dim3(256), 0, stream>>>(h3p, gwp, xl, gS);
    gcn_agg<<<dim3(128), dim3(256), 0, stream>>>(xl, ei, ew, gb, Tpre, gS, gS2);
    hipEventRecord(evJ0, s2);
    hipStreamWaitEvent(stream, evJ0, 0);   // join before finalize (needs l1)
  } else {
    gemm_nt<<<dim3(30, 4, 2), dim3(256), 0, stream>>>(Xb, lwb, l1, (float*)nullptr);
    gemm_nt<<<dim3(30, 4, 2), dim3(256), 0, stream>>>(h3p, gwp, xl, gS);
    gcn_agg<<<dim3(128), dim3(256), 0, stream>>>(xl, ei, ew, gb, Tpre, gS, gS2);
  }
  finalize_k<<<dim3(128), dim3(256), 0, stream>>>(Tpre, l1, gS, gS2,
                                                  gnms, gnw, gnb, lb, ow, ob,
                                                  (float*)d_out);
}

// Round 11
// 192.359 us; speedup vs baseline: 1.1827x; 1.1827x over previous
//
#include <hip/hip_runtime.h>

typedef unsigned short u16;
typedef unsigned int   u32;

typedef short shortx8   __attribute__((ext_vector_type(8)));
typedef float floatx4   __attribute__((ext_vector_type(4)));
typedef float floatx16  __attribute__((ext_vector_type(16)));
typedef u32   uintx2    __attribute__((ext_vector_type(2)));
typedef u32   uintx4    __attribute__((ext_vector_type(4)));

typedef u32     u32a     __attribute__((may_alias));
typedef uintx2  uintx2a  __attribute__((may_alias));
typedef uintx4  uintx4a  __attribute__((may_alias));
typedef shortx8 shortx8a __attribute__((may_alias));

// accurate round-to-nearest-even (weights)
__device__ __forceinline__ u16 f2bf(float f){
  union { float f; u32 i; } v; v.f = f;
  return (u16)((v.i + 0x7fffu + ((v.i >> 16) & 1u)) >> 16);
}
// fast round-half-up (scalar hot path; max 0.5 ulp)
__device__ __forceinline__ u16 f2bf_fast(float f){
  union { float f; u32 i; } v; v.f = f;
  return (u16)((v.i + 0x8000u) >> 16);
}
// pack two bf16 via v_perm (3 VALU ops) — fallback
__device__ __forceinline__ u32 pack2(float lo, float hi){
  union { float f; u32 i; } a, b; a.f = lo; b.f = hi;
  return __builtin_amdgcn_perm(b.i + 0x8000u, a.i + 0x8000u, 0x07060302u);
}
// packed f32->bf16 convert: 1 VALU op on gfx950 (v_cvt_pk_bf16_f32), RNE
__device__ __forceinline__ u32 cvtpk2(float lo, float hi){
#if __has_builtin(__builtin_amdgcn_cvt_pk_bf16_f32)
  auto pv = __builtin_amdgcn_cvt_pk_bf16_f32(lo, hi);
  if constexpr (sizeof(pv) == 4){
    u32 out; __builtin_memcpy(&out, &pv, 4); return out;
  } else {
    return pack2(lo, hi);
  }
#else
  return pack2(lo, hi);
#endif
}
__device__ __forceinline__ float lrelu(float v){ return fmaxf(v, 0.01f*v); }

// ---------------------------------------------------------------------------
// FINAL CONFIGURATION (R9 exact; session best, measured twice: 193.1 / 193.0
// µs). Structural experiments R1/R2/R3/R5/R6/R7/R8/R10 all landed 195-227.
// Kernel 1: fused conv1 -> conv2 -> conv3, all on MFMA — ROUND-16 structure.
// Also zeroes the xl/l1 split-K accumulators (one float per thread, exact
// coverage: 3840 blocks x 256 = 2 x 491,520).
// grid (16 t-pairs, 16 b-groups, 15 nodes), block 256 (2 wave-pairs).
// ---------------------------------------------------------------------------
__global__ void __launch_bounds__(256, 4) fused_conv(
    const float* __restrict__ X,
    const float* __restrict__ w1, const float* __restrict__ b1,
    const float* __restrict__ w2, const float* __restrict__ b2,
    const float* __restrict__ w3, const float* __restrict__ b3,
    u16* __restrict__ h3p, u16* __restrict__ Xb,
    const float* __restrict__ lw, u16* __restrict__ lwb,
    const float* __restrict__ gw, u16* __restrict__ gwp,
    float* __restrict__ xlz, float* __restrict__ l1z){
  const int tid  = threadIdx.x;
  const int node = blockIdx.z;
  const int p0   = blockIdx.x * 120;
  const int b0   = blockIdx.y * 8;

  // per-pair region: [0..1631] = H1 (68 rows x 24), [1632..4351] = H2 (68 x 40)
  // pads: H1 cols 16..23 = BtW rows 0..67; H2 cols 32..39 = BtW rows 68..135
  __shared__ __attribute__((aligned(16))) u16 sPair[2][4352];
  __shared__ __attribute__((aligned(16))) u16 sW2f[2560];   // [tap][kh][oc32][j8]
  __shared__ __attribute__((aligned(16))) u16 sW3f[160];    // [tap][ic32]
  __shared__ __attribute__((aligned(16))) u16 sXb[8*136];   // bf16 X window (120+16)
  __shared__ float sW1[80], sB1[16], sB2[32];

  // ---- distributed prep: 256 elements per block, exact coverage; also
  //      zero xl/l1 (split-K atomic accumulators) ----
  {
    const int bid = blockIdx.x + 16*(blockIdx.y + 16*blockIdx.z);  // 0..3839
    int gid = bid*256 + tid;                   // 0..983039
    if (gid < 491520){
      lwb[gid] = f2bf(lw[gid]);                // lin1_w: 256*1920 elements
      xlz[gid] = 0.f;
    } else {
      int g2 = gid - 491520;                   // 0..491519 (gwp elements)
      int row = g2 / 1920;                     // 0..255
      int col = g2 - row*1920;
      gwp[g2] = (col < 1908) ? f2bf(gw[row*1908 + col]) : (u16)0;
      l1z[g2] = 0.f;
    }
  }

  // ---- staging ----
  {
    const int bls = tid >> 5, i0 = tid & 31;   // 8 batches x 32 threads
    const float* xrow = X  + (size_t)((b0 + bls)*15 + node)*1920;
    u16*        xbrow = Xb + (size_t)((b0 + bls)*15 + node)*1920;
    #pragma unroll
    for (int u = 0; u < 5; ++u){
      int i = i0 + 32*u;
      if (i < 136){
        int g = p0 + i;
        float xv = (g < 1920) ? xrow[g] : 0.f;
        u16 xb = f2bf_fast(xv);
        sXb[bls*136 + i] = xb;
        if (i < 120) xbrow[g] = xb;   // i<120 => g<1920 always
      }
    }
    // w2 into 32x32 A-frag order: idx = ((tap*2 + kh)*32 + oc)*8 + j
    #pragma unroll
    for (int u = 0; u < 10; ++u){
      int d = tid + 256*u;
      int j = d & 7, oc = (d >> 3) & 31, kh = (d >> 8) & 1, tap = d >> 9; // 0..4
      sW2f[d] = f2bf(w2[node*2560 + (oc*16 + kh*8 + j)*5 + tap]);
    }
    if (tid < 160){
      int icc = tid / 5, tp = tid - 5*icc;
      sW3f[tp*32 + icc] = f2bf(w3[node*160 + tid]);
    }
    if (tid < 80) sW1[tid] = w1[node*80 + tid];
    if (tid < 16) sB1[tid] = b1[node*16 + tid];
    if (tid < 32) sB2[tid] = b2[node*32 + tid];
    // zero sH2 tail rows 64..67, cols 0..31 ONLY (cols 32..39 are BtW pad —
    // must not race with the per-bb BtW build). 2 pairs x 128 u16 = 256.
    {
      const int pr = tid >> 7, idx = tid & 127;
      sPair[pr][1632 + (64 + (idx >> 5))*40 + (idx & 31)] = 0;
    }
  }
  __syncthreads();

  const int w = tid >> 6, lane = tid & 63;
  const int pw = w >> 1, ph = w & 1;          // pair index (0..1) / pair half
  const int m = lane & 15, quad = lane >> 4;  // 16x16 roles
  const int t32 = lane & 31, kh = lane >> 5;  // 32x32 roles (kh = k-half)

  // conv2 A-frags (32x32x16): A[m=oc=lane&31][k=kh*8+j]
  shortx8 a2t[5];
  #pragma unroll
  for (int tap = 0; tap < 5; ++tap)
    a2t[tap] = *(const shortx8a*)&sW2f[((tap*2 + kh)*32 + t32)*8];

  // conv2 bias per accumulator reg: row(oc) = (r&3) + 8*(r>>2) + 4*kh
  float biasr[16];
  #pragma unroll
  for (int r = 0; r < 16; ++r)
    biasr[r] = sB2[(r&3) + 8*(r>>2) + 4*kh];

  // conv3 A-frags (16x16x32): only row m=0 nonzero
  shortx8 a3[5];
  {
    const shortx8 zv = {0,0,0,0,0,0,0,0};
    #pragma unroll
    for (int tp = 0; tp < 5; ++tp){
      shortx8 t = *(const shortx8a*)&sW3f[tp*32 + quad*8];
      a3[tp] = (m == 0) ? t : zv;
    }
  }
  const float b3v = b3[node];

  // conv1 A-frags (16x16x32): A[oc=lane&15][k=quad*8+j], taps k<5 only ->
  // quad 0 carries data, quads 1..3 zero. hi+lo bf16 split of f32 weights.
  shortx8 a1h = {0,0,0,0,0,0,0,0}, a1l = {0,0,0,0,0,0,0,0};
  if (quad == 0){
    const float* wrow = sW1 + m*5;
    #pragma unroll
    for (int j = 0; j < 5; ++j){
      float wv = wrow[j];
      u16 h = f2bf(wv);
      union { u32 i; float f; } hf; hf.i = ((u32)h) << 16;
      u16 l = f2bf(wv - hf.f);
      a1h[j] = (short)h; a1l[j] = (short)l;
    }
  }
  // conv1 bias per acc reg: D row(oc) = quad*4 + r
  float biasA[4];
  #pragma unroll
  for (int r = 0; r < 4; ++r) biasA[r] = sB1[quad*4 + r];

  u16* h1w = sPair[pw];           // pair region base (H1 at 0, H2 at 1632)
  u16* h2w = sPair[pw] + 1632;

  for (int bb = 0; bb < 4; ++bb){
    const int bl = pw + bb*2;   // 0..7
    const int rg = (b0 + bl)*15 + node;

    // ---- build BtW im2col rows into the H1/H2 pads (once per bb) ----
    // BtW[t][k] = sXb[bl*136 + t + k], t 0..135, k 0..7 (zero beyond window).
    {
      const int s = tid & 127;                 // lane-in-pair
      if (s < 68){
        const u32* xb32 = (const u32*)sXb + bl*68;
        u32 r0 = xb32[s];
        u32 r1 = (s+1 < 68) ? xb32[s+1] : 0u;
        u32 r2 = (s+2 < 68) ? xb32[s+2] : 0u;
        u32 r3 = (s+3 < 68) ? xb32[s+3] : 0u;
        u32 r4 = (s+4 < 68) ? xb32[s+4] : 0u;
        const int te = 2*s, to = 2*s + 1;      // both rows same region (s<34)
        const int offE = (s < 34) ? te*24 + 16 : 1632 + (te - 68)*40 + 32;
        const int offO = (s < 34) ? to*24 + 16 : 1632 + (to - 68)*40 + 32;
        uintx4 ve = {r0, r1, r2, r3};
        uintx4 vo = {__builtin_amdgcn_alignbit(r1, r0, 16),
                     __builtin_amdgcn_alignbit(r2, r1, 16),
                     __builtin_amdgcn_alignbit(r3, r2, 16),
                     __builtin_amdgcn_alignbit(r4, r3, 16)};
        *(uintx4a*)(h1w + offE) = ve;
        *(uintx4a*)(h1w + offO) = vo;
      }
    }
    __syncthreads();   // BtW build -> conv1 frag reads

    #pragma unroll
    for (int tt = 0; tt < 2; ++tt){
      const int p = p0 + tt*60;

      // ---- conv1 (MFMA 16x16x32): D[oc][t] tiles of 16 t; wave ph=0 does
      // tiles {0,2,4}, ph=1 does {1,3}; 2 MFMAs (w1 lo+hi) per tile ----
      #pragma unroll
      for (int ti = 0; ti < 3; ++ti){
        const int T = ph + 2*ti;
        if (T < 5){
          const int tr = T*16 + m;             // output t (valid < 68)
          int row = tt*60 + tr;                // BtW row
          row = row > 135 ? 135 : row;         // clamp (garbage rows guarded)
          shortx8 bfr = {0,0,0,0,0,0,0,0};
          if (quad == 0){
            const int off = (row < 68) ? row*24 + 16 : 1632 + (row - 68)*40 + 32;
            bfr = *(const shortx8a*)(h1w + off);
          }
          floatx4 acc = {biasA[0], biasA[1], biasA[2], biasA[3]};
          acc = __builtin_amdgcn_mfma_f32_16x16x32_bf16(a1l, bfr, acc, 0, 0, 0);
          acc = __builtin_amdgcn_mfma_f32_16x16x32_bf16(a1h, bfr, acc, 0, 0, 0);
          if (tr < 68){
            uintx2 pk = { cvtpk2(lrelu(acc[0]), lrelu(acc[1])),
                          cvtpk2(lrelu(acc[2]), lrelu(acc[3])) };
            *(uintx2a*)(h1w + tr*24 + quad*4) = pk;   // [t][oc] b64, 8B aligned
          }
        }
      }
      __syncthreads();   // conv1 writes -> conv2 reads

      // ---- conv2 (32x32x16): tile nt=ph, 5 tap MFMAs, bias in acc ----
      {
        const int t0 = ph*32;
        floatx16 acc;
        #pragma unroll
        for (int r = 0; r < 16; ++r) acc[r] = biasr[r];
        #pragma unroll
        for (int tap = 0; tap < 5; ++tap){
          shortx8 bfr = *(const shortx8a*)(h1w + (t0 + t32 + tap)*24 + kh*8);
          acc = __builtin_amdgcn_mfma_f32_32x32x16_bf16(a2t[tap], bfr, acc, 0, 0, 0);
        }
        // D: col(t)=lane&31, row(oc)=(r&3)+8*(r>>2)+4*kh; r-pairs = oc pairs
        u16* dst = h2w + (t0 + t32)*40;
        #pragma unroll
        for (int r = 0; r < 16; r += 2){
          float v0 = lrelu(acc[r]);
          float v1 = lrelu(acc[r+1]);
          const int oc0 = (r&3) + 8*(r>>2) + 4*kh;
          *(u32a*)(dst + oc0) = cvtpk2(v0, v1);
        }
      }
      __syncthreads();   // conv2 writes -> conv3 reads

      // ---- conv3 (16x16x32): tiles {2ph, 2ph+1}, 5 tap MFMAs; D row 0 ----
      #pragma unroll
      for (int i = 0; i < 2; ++i){
        const int nt = 2*ph + i;
        floatx4 acc3 = {0.f,0.f,0.f,0.f};
        if (lane < 16) acc3[0] = b3v;
        #pragma unroll
        for (int tp = 0; tp < 5; ++tp){
          shortx8 bfr = *(const shortx8a*)(h2w + (nt*16 + m + tp)*40 + quad*8);
          acc3 = __builtin_amdgcn_mfma_f32_16x16x32_bf16(a3[tp], bfr, acc3, 0, 0, 0);
        }
        const int tl = nt*16 + lane;
        if (lane < 16 && tl < 60){
          const int t3 = p + tl;           // max 15*120+60+59 = 1919 < 1920
          float v = lrelu(acc3[0]);
          h3p[(size_t)rg*1920 + t3] = (t3 < 1908) ? f2bf_fast(v) : (u16)0;
        }
      }
    }
  }
}

// ---------------------------------------------------------------------------
// Kernel 2: NT GEMM, split-K x2 + ping-pong LDS (round-18 / R4 config —
// measured best). grid (30,4,4): z = job*2 + khalf, each block K=960
// (15 iters), 480 blocks ~1.9/CU. atomicAdd outputs into pre-zeroed xl/l1
// (2-way per address). Block (0,0,0) zeroes gS/gS2 (30KB).
// ---------------------------------------------------------------------------
__global__ void __launch_bounds__(256) gemm_nt(
    const u16* __restrict__ A0, const u16* __restrict__ B0, float* __restrict__ O0,
    const u16* __restrict__ A1, const u16* __restrict__ B1, float* __restrict__ O1,
    float* __restrict__ gZ){
  const int job = blockIdx.z >> 1, khf = blockIdx.z & 1;
  const u16* A; const u16* Bm; float* O;
  if (job == 0){ A = A0; Bm = B0; O = O0; } else { A = A1; Bm = B1; O = O1; }
  __shared__ __attribute__((aligned(16))) u16 sA[2][64*88];
  __shared__ __attribute__((aligned(16))) u16 sB[2][64*88];
  const int tid = threadIdx.x;
  if (blockIdx.x == 0 && blockIdx.y == 0 && blockIdx.z == 0){
    #pragma unroll
    for (int u = 0; u < 30; ++u) gZ[tid + 256*u] = 0.f;
  }
  const int m0 = blockIdx.x*64, n0 = blockIdx.y*64;
  const int row = tid >> 2, kc = tid & 3;
  const int w = tid >> 6, lane = tid & 63;
  const int m = lane & 15, quad = lane >> 4;
  const int mo = (w & 1)*32, no = (w >> 1)*32;
  floatx4 acc[2][2];
  #pragma unroll
  for (int i = 0; i < 2; ++i)
    #pragma unroll
    for (int j = 0; j < 2; ++j)
      #pragma unroll
      for (int r = 0; r < 4; ++r) acc[i][j][r] = 0.f;

  const u16* ap = A  + (size_t)(m0 + row)*1920 + khf*960 + kc*8;
  const u16* bp = Bm + (size_t)(n0 + row)*1920 + khf*960 + kc*8;
  // preload kt=0
  uintx4 va0 = *(const uintx4a*)ap;
  uintx4 va1 = *(const uintx4a*)(ap + 32);
  uintx4 vb0 = *(const uintx4a*)bp;
  uintx4 vb1 = *(const uintx4a*)(bp + 32);
  ap += 64; bp += 64;

  for (int kt = 0; kt < 15; ++kt){
    const int c = kt & 1;
    *(uintx4a*)&sA[c][row*88 + kc*8]      = va0;
    *(uintx4a*)&sA[c][row*88 + 32 + kc*8] = va1;
    *(uintx4a*)&sB[c][row*88 + kc*8]      = vb0;
    *(uintx4a*)&sB[c][row*88 + 32 + kc*8] = vb1;
    __syncthreads();
    if (kt < 14){
      va0 = *(const uintx4a*)ap;
      va1 = *(const uintx4a*)(ap + 32);
      vb0 = *(const uintx4a*)bp;
      vb1 = *(const uintx4a*)(bp + 32);
      ap += 64; bp += 64;
    }
    #pragma unroll
    for (int ks = 0; ks < 64; ks += 32){
      const shortx8 af0 = *(const shortx8a*)&sA[c][(mo      + m)*88 + ks + quad*8];
      const shortx8 af1 = *(const shortx8a*)&sA[c][(mo + 16 + m)*88 + ks + quad*8];
      const shortx8 bf0 = *(const shortx8a*)&sB[c][(no      + m)*88 + ks + quad*8];
      const shortx8 bf1 = *(const shortx8a*)&sB[c][(no + 16 + m)*88 + ks + quad*8];
      acc[0][0] = __builtin_amdgcn_mfma_f32_16x16x32_bf16(af0, bf0, acc[0][0], 0, 0, 0);
      acc[0][1] = __builtin_amdgcn_mfma_f32_16x16x32_bf16(af0, bf1, acc[0][1], 0, 0, 0);
      acc[1][0] = __builtin_amdgcn_mfma_f32_16x16x32_bf16(af1, bf0, acc[1][0], 0, 0, 0);
      acc[1][1] = __builtin_amdgcn_mfma_f32_16x16x32_bf16(af1, bf1, acc[1][1], 0, 0, 0);
    }
    // ping-pong: buf c rewritten only at kt+2; reads complete before the
    // kt+1 barrier in same-wave program order.
  }
  #pragma unroll
  for (int mi = 0; mi < 2; ++mi)
    #pragma unroll
    for (int ni = 0; ni < 2; ++ni)
      #pragma unroll
      for (int r = 0; r < 4; ++r){
        int rr = m0 + mo + mi*16 + quad*4 + r;
        int cc = n0 + no + ni*16 + m;
        atomicAdd(&O[(size_t)rr*256 + cc], acc[mi][ni][r]);
      }
}

// ---------------------------------------------------------------------------
// Kernel 3: GCN aggregation + bias, plus per-(n,c) GraphNorm stat
// accumulation (atomicAdd of T and T^2 into gS/gS2, zeroed by gemm_nt).
// ---------------------------------------------------------------------------
__global__ void __launch_bounds__(256) gcn_agg(
    const float* __restrict__ xl, const int* __restrict__ ei,
    const float* __restrict__ ew, const float* __restrict__ gcn_b,
    float* __restrict__ Tpre, float* __restrict__ gS, float* __restrict__ gS2){
  const int b = blockIdx.x, tid = threadIdx.x;
  __shared__ float sxl[15*256];
  __shared__ float s_deg[15], s_dinv[15], s_norm[71];
  __shared__ int   s_cnt[15], s_start[16], s_fill[15], s_srcl[71];
  if (tid < 15){ s_deg[tid] = 0.f; s_cnt[tid] = 0; s_fill[tid] = 0; }
  #pragma unroll
  for (int n = 0; n < 15; ++n)
    sxl[n*256 + tid] = xl[(size_t)(b*15 + n)*256 + tid];
  __syncthreads();
  int se = 0, de = 0; float we = 0.f;
  if (tid < 71){
    if (tid < 56){ se = ei[tid]; de = ei[56 + tid]; we = ew[tid]; }
    else         { se = tid - 56; de = tid - 56; we = 1.0f; }
    atomicAdd(&s_deg[de], we);
    atomicAdd(&s_cnt[de], 1);
  }
  __syncthreads();
  if (tid < 15) s_dinv[tid] = s_deg[tid] > 0.f ? rsqrtf(s_deg[tid]) : 0.f;
  if (tid == 0){
    int a = 0;
    for (int n = 0; n < 15; ++n){ s_start[n] = a; a += s_cnt[n]; }
    s_start[15] = a;
  }
  __syncthreads();
  if (tid < 71){
    float nrm = s_dinv[se]*we*s_dinv[de];
    int pos = s_start[de] + atomicAdd(&s_fill[de], 1);
    s_srcl[pos] = se; s_norm[pos] = nrm;
  }
  __syncthreads();
  const float gb = gcn_b[tid];
  for (int n = 0; n < 15; ++n){
    float acc = gb;
    const int e0 = s_start[n], e1 = s_start[n+1];
    for (int idx = e0; idx < e1; ++idx)
      acc += s_norm[idx]*sxl[s_srcl[idx]*256 + tid];
    Tpre[(size_t)(b*15 + n)*256 + tid] = acc;
    atomicAdd(&gS [n*256 + tid], acc);
    atomicAdd(&gS2[n*256 + tid], acc*acc);
  }
}

// ---------------------------------------------------------------------------
// Kernel 4: GraphNorm (stats from gS/gS2) + lin1-add + ELU + pool + head
// ---------------------------------------------------------------------------
__global__ void __launch_bounds__(256) finalize_k(
    const float* __restrict__ Tpre, const float* __restrict__ l1,
    const float* __restrict__ gS, const float* __restrict__ gS2,
    const float* __restrict__ gn_ms, const float* __restrict__ gn_w,
    const float* __restrict__ gn_b, const float* __restrict__ lin1_b,
    const float* __restrict__ out_w, const float* __restrict__ out_b,
    float* __restrict__ dout){
  const int b = blockIdx.x, tid = threadIdx.x;
  __shared__ float spool[256], spart[256];
  const float gnb = gn_b[tid], lb = lin1_b[tid];
  const float gms = gn_ms[tid], gwc = gn_w[tid];
  float acc = 0.f;
  #pragma unroll
  for (int n = 0; n < 15; ++n){
    const float s  = gS [n*256 + tid];
    const float s2 = gS2[n*256 + tid];
    const float mean = s*(1.f/128.f);
    const float mo   = mean*gms;
    float var = s2*(1.f/128.f) - 2.f*mo*mean + mo*mo;
    var = fmaxf(var, 0.f);
    const float scal = gwc*rsqrtf(var + 1e-5f);
    float t = (Tpre[(size_t)(b*15 + n)*256 + tid] - mo)*scal
              + gnb + l1[(size_t)(b*15 + n)*256 + tid] + lb;
    t = t > 0.f ? t : (__expf(t) - 1.f);   // ELU(alpha=1)
    acc += t;
  }
  const float pool = acc*(1.f/15.f);
  dout[b*256 + tid] = pool;
  spool[tid] = pool;
  __syncthreads();
  const int j = tid >> 4, q = tid & 15;
  float s = 0.f;
  for (int i = 0; i < 16; ++i){
    int cc = q + i*16;
    s += spool[cc]*out_w[j*256 + cc];
  }
  spart[tid] = s;
  __syncthreads();
  if (tid < 16){
    float tot = out_b[tid];
    #pragma unroll
    for (int i = 0; i < 16; ++i) tot += spart[tid*16 + i];
    dout[32768 + b*16 + tid] = tot;
  }
}

// ---------------------------------------------------------------------------
extern "C" void kernel_launch(void* const* d_in, const int* in_sizes, int n_in,
                              void* d_out, int out_size, void* d_ws, size_t ws_size,
                              hipStream_t stream){
  (void)in_sizes; (void)n_in; (void)out_size; (void)ws_size;
  const float* X    = (const float*)d_in[0];
  const int*   ei   = (const int*)d_in[1];
  const float* ew   = (const float*)d_in[2];
  const float* w1   = (const float*)d_in[3];
  const float* b1   = (const float*)d_in[4];
  const float* w2   = (const float*)d_in[5];
  const float* b2   = (const float*)d_in[6];
  const float* w3   = (const float*)d_in[7];
  const float* b3   = (const float*)d_in[8];
  const float* gw   = (const float*)d_in[9];
  const float* gb   = (const float*)d_in[10];
  const float* lw   = (const float*)d_in[11];
  const float* lb   = (const float*)d_in[12];
  const float* gnw  = (const float*)d_in[13];
  const float* gnb  = (const float*)d_in[14];
  const float* gnms = (const float*)d_in[15];
  const float* ow   = (const float*)d_in[16];
  const float* ob   = (const float*)d_in[17];

  char* ws = (char*)d_ws;
  u16*   h3p  = (u16*)(ws + 0);              //  7,372,800 B
  u16*   gwp  = (u16*)(ws + 7372800);        //    983,040 B (491,520 u16)
  u16*   Xb   = (u16*)(ws + 8355840);        //  7,372,800 B
  u16*   lwb  = (u16*)(ws + 15728640);       //    983,040 B (491,520 u16)
  float* xl   = (float*)(ws + 16711680);     //  1,966,080 B
  float* l1   = (float*)(ws + 18677760);     //  1,966,080 B
  float* gS   = (float*)(ws + 20643840);     //     15,360 B
  float* gS2  = (float*)(ws + 20659200);     //     15,360 B (end 20,674,560)
  float* Tpre = (float*)(ws + 0);            // reuse h3p (dead after gemm)

  fused_conv<<<dim3(16, 16, 15), dim3(256), 0, stream>>>(X, w1, b1, w2, b2, w3, b3,
                                                         h3p, Xb, lw, lwb, gw, gwp,
                                                         xl, l1);
  gemm_nt   <<<dim3(30, 4, 4),   dim3(256), 0, stream>>>(Xb, lwb, l1, h3p, gwp, xl, gS);
  gcn_agg   <<<dim3(128),        dim3(256), 0, stream>>>(xl, ei, ew, gb, Tpre, gS, gS2);
  finalize_k<<<dim3(128),        dim3(256), 0, stream>>>(Tpre, l1, gS, gS2,
                                                         gnms, gnw, gnb, lb, ow, ob,
                                                         (float*)d_out);
}